// Round 4
// baseline (308.176 us; speedup 1.0000x reference)
//
#include <hip/hip_runtime.h>
#include <cstdint>

#define DIM 128
#define MTILE 64        // edges/nodes per block-tile
#define PAIR_LD 264     // ushorts per pair row (256 + 8 pad) -- fallback kernel
#define H_LD 136        // ushorts per h row  (128 + 8 pad)

typedef __bf16 v8bf __attribute__((ext_vector_type(8)));
typedef _Float16 v8hf __attribute__((ext_vector_type(8)));
typedef float v16f __attribute__((ext_vector_type(16)));

static __device__ __forceinline__ unsigned int f2bf_pack(float a, float b) {
  union { float f; unsigned u; } x, y; x.f = a; y.f = b;
  unsigned lo = (x.u + 0x7FFFu + ((x.u >> 16) & 1u)) >> 16;
  unsigned hi = (y.u + 0x7FFFu + ((y.u >> 16) & 1u)) >> 16;
  return lo | (hi << 16);
}
static __device__ __forceinline__ unsigned short f2bf(float a) {
  union { float f; unsigned u; } x; x.f = a;
  return (unsigned short)((x.u + 0x7FFFu + ((x.u >> 16) & 1u)) >> 16);
}
static __device__ __forceinline__ unsigned short f2h(float a) {
  union { _Float16 h; unsigned short u; } c; c.h = (_Float16)a; return c.u;
}
static __device__ __forceinline__ float bfhi2f(unsigned int hi16) {
  union { unsigned u; float f; } c; c.u = hi16; return c.f;
}

// prep: weight transpose/convert only. W1t bf16 (node_precompute / fallback
// GEMM1); W2t fp16 when y-cached path runs, bf16 for the fallback.
__global__ __launch_bounds__(256) void prep_w(
    const float* __restrict__ W1, const float* __restrict__ W2,
    unsigned short* __restrict__ W1t, unsigned short* __restrict__ W2t,
    int w2_f16) {
  int i = blockIdx.x * 256 + threadIdx.x;
  if (i < 32768) {
    int n = i >> 8, k = i & 255;
    W1t[i] = f2bf(W1[k * 128 + n]);
  } else if (i < 49152) {
    int j = i - 32768;
    int n = j >> 7, k = j & 127;
    float v = W2[k * 128 + n];
    W2t[j] = w2_f16 ? f2h(v) : f2bf(v);
  }
}

// node_precompute v2 (kept): `which` split across the grid. Per block:
// 8 B1 fragments (32 VGPR), one stage->MFMA->store pass, 4 blocks/CU.
// y stored fp16; b1 folded into y2 only.
__global__ __launch_bounds__(256, 4) void node_precompute(
    const float* __restrict__ x1, const float* __restrict__ x2,
    const unsigned short* __restrict__ W1t, const float* __restrict__ b1,
    unsigned short* __restrict__ y1c, unsigned short* __restrict__ y2c,
    int nnodes)
{
  __shared__ unsigned short sm_x[MTILE * H_LD];
  __shared__ unsigned short sm_y[MTILE * H_LD];

  const int tid = threadIdx.x;
  const int lane = tid & 63;
  const int wv = tid >> 6;
  const int l31 = lane & 31;
  const int l5 = lane >> 5;
  const int nb = wv * 32 + l31;
  const int rslot = tid >> 4;
  const int lane16 = tid & 15;

  const int which = blockIdx.x & 1;          // 0: y1 = x1@W1_top, 1: y2 = x2@W1_bot + b1
  const int base = (blockIdx.x >> 1) * MTILE;
  const int nvalid = nnodes - base;          // < 64 only in the last tile
  const float* xs = which ? x2 : x1;
  unsigned short* yd = which ? y2c : y1c;

  v8bf B1[8];
#pragma unroll
  for (int kt = 0; kt < 8; ++kt)
    B1[kt] = *reinterpret_cast<const v8bf*>(W1t + nb * 256 + which * 128 + kt * 16 + l5 * 8);
  const float badd = which ? b1[nb] : 0.f;

  // stage x tile (fp32 -> bf16), coalesced 32B/thread
#pragma unroll
  for (int p = 0; p < 4; ++p) {
    int el = p * 16 + rslot;
    int row = base + el; if (row >= nnodes) row = nnodes - 1;
    const float4* s = reinterpret_cast<const float4*>(xs + (size_t)row * DIM) + lane16 * 2;
    float4 f0 = s[0];
    float4 f1 = s[1];
    uint4 pk;
    pk.x = f2bf_pack(f0.x, f0.y);
    pk.y = f2bf_pack(f0.z, f0.w);
    pk.z = f2bf_pack(f1.x, f1.y);
    pk.w = f2bf_pack(f1.z, f1.w);
    *reinterpret_cast<uint4*>(&sm_x[el * H_LD + lane16 * 8]) = pk;
  }
  __syncthreads();

  // y-half = x @ W1_half, fp16 out into sm_y
#pragma unroll
  for (int h = 0; h < 2; ++h) {
    v16f acc;
#pragma unroll
    for (int r = 0; r < 16; ++r) acc[r] = 0.f;
#pragma unroll
    for (int kt = 0; kt < 8; ++kt) {
      v8bf a = *reinterpret_cast<const v8bf*>(&sm_x[(32 * h + l31) * H_LD + kt * 16 + l5 * 8]);
      acc = __builtin_amdgcn_mfma_f32_32x32x16_bf16(a, B1[kt], acc, 0, 0, 0);
    }
#pragma unroll
    for (int r = 0; r < 16; ++r) {
      int m = 32 * h + (r & 3) + 8 * (r >> 2) + 4 * l5;  // C/D row map (m74/m101)
      sm_y[m * H_LD + nb] = f2h(acc[r] + badd);
    }
  }
  __syncthreads();

  // coalesced fp16 write-out
#pragma unroll
  for (int p = 0; p < 4; ++p) {
    int el = p * 16 + rslot;
    if (el < nvalid)
      *reinterpret_cast<uint4*>(yd + (size_t)(base + el) * DIM + lane16 * 8) =
          *reinterpret_cast<const uint4*>(&sm_y[el * H_LD + lane16 * 8]);
  }
}

// Round-10 edge kernel: SOFTWARE-PIPELINED gather.
// Round-3 evidence: grid 1024->2048 was a null (113us, 3.44TB/s, occ 37%)
// -> per-wave memory parallelism is the limiter: each wave's 8 gather loads
// were consumed (vmcnt-waited) immediately, so they were in flight ~10% of
// the tile period. New schedule issues tile t+1's gathers right after tile
// t's data retires to LDS, so they fly across the whole GEMM2+GEMM3 phase.
// The 32-reg av/bv payload is held across the MFMA region; to stay under
// the (256,4) 128-reg cap, w3/b2 (32 regs) move to LDS as packed float2
// (half-wave-uniform broadcast reads). Predicted peak ~100 VGPR.
// Tripwire: WRITE_SIZE must stay 6250 KB (spill = scratch writes).
__global__ __launch_bounds__(256, 4) void mlp_edge_y(
    const int* __restrict__ eidx,
    const unsigned short* __restrict__ W2t,   // fp16 [n=128][k=128]
    const float* __restrict__ b2, const float* __restrict__ W3,
    const float* __restrict__ b3, float* __restrict__ out,
    int E, int ntiles,
    const unsigned short* __restrict__ y1c, const unsigned short* __restrict__ y2c)
{
  __shared__ unsigned short sm_h1[MTILE * H_LD];   // 17408 B
  __shared__ float sm_part[4 * MTILE];             // 1024 B
  __shared__ float2 sm_bw[DIM];                    // 1024 B: {b2[n], W3[n]}

  const int tid = threadIdx.x;
  const int lane = tid & 63;
  const int wv = tid >> 6;        // wave -> n-slice [32*wv, 32*wv+32)
  const int l31 = lane & 31;
  const int l5 = lane >> 5;
  const int nb = wv * 32 + l31;

  if (tid < 128) sm_bw[tid] = make_float2(b2[tid], W3[tid]);

  v8hf B2[8];
#pragma unroll
  for (int kt = 0; kt < 8; ++kt)
    B2[kt] = *reinterpret_cast<const v8hf*>(W2t + nb * 128 + kt * 16 + l5 * 8);
  const float bias3 = b3[0];
  const int n2b = wv * 32 + 4 * l5;   // n2(r) = n2b + (r&3) + 8*(r>>2)

  const int rslot = tid >> 4;     // 0..15: edge-row slot within a pass
  const int lane16 = tid & 15;    // 16 lanes x 8 fp16 cover one 128-wide row
  const int G = gridDim.x;

  if (ntiles <= 0) return;

  // ---- pipeline preamble ----
  // idxr = idx(t0); issue gathers(t0); idxr = idx(t0+G)
  int idxr[8];
  uint4 av[4], bv[4];
  {
    const int t0 = min((int)blockIdx.x, ntiles - 1);
    const size_t e0 = (size_t)t0 * MTILE;
#pragma unroll
    for (int p = 0; p < 8; ++p) {
      int el = (p & 3) * 16 + rslot;
      idxr[p] = eidx[e0 + el + ((p >= 4) ? (size_t)E : 0)];
    }
#pragma unroll
    for (int p = 0; p < 4; ++p) {
      av[p] = *reinterpret_cast<const uint4*>(y1c + (size_t)idxr[p] * DIM + lane16 * 8);
      bv[p] = *reinterpret_cast<const uint4*>(y2c + (size_t)idxr[p + 4] * DIM + lane16 * 8);
    }
    const int t1 = min((int)blockIdx.x + G, ntiles - 1);
    const size_t e1 = (size_t)t1 * MTILE;
#pragma unroll
    for (int p = 0; p < 8; ++p) {
      int el = (p & 3) * 16 + rslot;
      idxr[p] = eidx[e1 + el + ((p >= 4) ? (size_t)E : 0)];
    }
  }

  int eprev = -1;

  for (int tile = blockIdx.x; tile < ntiles; tile += G) {
    __syncthreads();  // A: sm_h1 free (GEMM2 readers done), sm_part ready

    // deferred final reduce of PREVIOUS tile
    if (eprev >= 0 && tid < MTILE) {
      float s = sm_part[tid] + sm_part[64 + tid] + sm_part[128 + tid] + sm_part[192 + tid];
      out[eprev + tid] = s + bias3;
    }

    // retire tile t's gathered data: h1 = relu(y1 + y2) -> LDS
    // (this is the only vmcnt wait on av/bv -- issued one full tile ago)
#pragma unroll
    for (int p = 0; p < 4; ++p) {
      union { uint4 u; v8hf h; } a, b;
      a.u = av[p]; b.u = bv[p];
      v8hf s = a.h + b.h;
#pragma unroll
      for (int j = 0; j < 8; ++j) s[j] = s[j] > (_Float16)0 ? s[j] : (_Float16)0;
      union { v8hf h; uint4 u; } r; r.h = s;
      int el = p * 16 + rslot;
      *reinterpret_cast<uint4*>(&sm_h1[el * H_LD + lane16 * 8]) = r.u;
    }

    // issue tile t+G's gathers NOW -- they fly across GEMM2+GEMM3
    if (tile + G < ntiles) {
#pragma unroll
      for (int p = 0; p < 4; ++p) {
        av[p] = *reinterpret_cast<const uint4*>(y1c + (size_t)idxr[p] * DIM + lane16 * 8);
        bv[p] = *reinterpret_cast<const uint4*>(y2c + (size_t)idxr[p + 4] * DIM + lane16 * 8);
      }
      // prefetch idx(t+2G) for next iteration's gather issue
      const int tn = min(tile + 2 * G, ntiles - 1);
      const size_t en = (size_t)tn * MTILE;
#pragma unroll
      for (int p = 0; p < 8; ++p) {
        int el = (p & 3) * 16 + rslot;
        idxr[p] = eidx[en + el + ((p >= 4) ? (size_t)E : 0)];
      }
    }
    __syncthreads();  // B: h1 ready

    // GEMM2 (transposed: h2^T = W2t @ h1^T) + GEMM3 via LDS-resident b2/W3
#pragma unroll
    for (int h = 0; h < 2; ++h) {
      v16f acc;
#pragma unroll
      for (int r = 0; r < 16; ++r) acc[r] = 0.f;
#pragma unroll
      for (int kt = 0; kt < 8; ++kt) {
        v8hf bf = *reinterpret_cast<const v8hf*>(&sm_h1[(32 * h + l31) * H_LD + kt * 16 + l5 * 8]);
        acc = __builtin_amdgcn_mfma_f32_32x32x16_f16(B2[kt], bf, acc, 0, 0, 0);
      }
      float p = 0.f;
#pragma unroll
      for (int r = 0; r < 16; ++r) {
        float2 bw = sm_bw[n2b + (r & 3) + 8 * (r >> 2)];  // broadcast read
        p += fmaxf(acc[r] + bw.x, 0.f) * bw.y;
      }
      p += __shfl_xor(p, 32);          // combine l5 halves
      if (l5 == 0) sm_part[wv * 64 + 32 * h + l31] = p;
    }

    eprev = tile * MTILE;
  }

  // ---- epilogue: reduce the last tile's partials ----
  __syncthreads();
  if (eprev >= 0 && tid < MTILE) {
    float s = sm_part[tid] + sm_part[64 + tid] + sm_part[128 + tid] + sm_part[192 + tid];
    out[eprev + tid] = s + bias3;
  }
}

// Fallback (ws too small for y cache): unchanged round-6 structure.
__global__ __launch_bounds__(256, 2) void mlp_edge_direct(
    const float* __restrict__ x1, const float* __restrict__ x2,
    const int* __restrict__ eidx,
    const unsigned short* __restrict__ W1t, const unsigned short* __restrict__ W2t,
    const float* __restrict__ b1, const float* __restrict__ b2,
    const float* __restrict__ W3, const float* __restrict__ b3,
    float* __restrict__ out, int E, int ntiles)
{
  __shared__ unsigned short sm_pair[MTILE * PAIR_LD];
  __shared__ unsigned short sm_h1[MTILE * H_LD];
  __shared__ float sm_w3[4 * 36];
  unsigned short* sm_h2 = sm_pair;

  const int tid = threadIdx.x;
  const int lane = tid & 63;
  const int wv = tid >> 6;
  const int l31 = lane & 31;
  const int l5 = lane >> 5;
  const int nb = wv * 32 + l31;

  v8bf B1[16], B2[8];
#pragma unroll
  for (int kt = 0; kt < 16; ++kt)
    B1[kt] = *reinterpret_cast<const v8bf*>(W1t + nb * 256 + kt * 16 + l5 * 8);
#pragma unroll
  for (int kt = 0; kt < 8; ++kt)
    B2[kt] = *reinterpret_cast<const v8bf*>(W2t + nb * 128 + kt * 16 + l5 * 8);
  const float b1v = b1[nb];
  const float b2v = b2[nb];
  const float bias3 = b3[0];
  if (tid < 128) sm_w3[(tid >> 5) * 36 + (tid & 31)] = W3[tid];

  const int rslot = tid >> 4;
  const int lane16 = tid & 15;
  const int part = tid & 3;

  for (int tile = blockIdx.x; tile < ntiles; tile += gridDim.x) {
    __syncthreads();
    const int e0 = tile * MTILE;
#pragma unroll
    for (int p = 0; p < 8; ++p) {
      int rowid = p * 16 + rslot;
      int half = rowid >> 6;
      int el = rowid & 63;
      int node = eidx[e0 + el + (half ? E : 0)];
      const float* src = (half ? x2 : x1) + (size_t)node * DIM + lane16 * 8;
      float4 f0 = *reinterpret_cast<const float4*>(src);
      float4 f1 = *reinterpret_cast<const float4*>(src + 4);
      uint4 pk;
      pk.x = f2bf_pack(f0.x, f0.y);
      pk.y = f2bf_pack(f0.z, f0.w);
      pk.z = f2bf_pack(f1.x, f1.y);
      pk.w = f2bf_pack(f1.z, f1.w);
      *reinterpret_cast<uint4*>(&sm_pair[el * PAIR_LD + half * 128 + lane16 * 8]) = pk;
    }
    __syncthreads();

    v16f acc0, acc1;
#pragma unroll
    for (int r = 0; r < 16; ++r) { acc0[r] = 0.f; acc1[r] = 0.f; }
#pragma unroll
    for (int kt = 0; kt < 16; ++kt) {
      v8bf a0 = *reinterpret_cast<const v8bf*>(&sm_pair[l31 * PAIR_LD + kt * 16 + l5 * 8]);
      v8bf a1 = *reinterpret_cast<const v8bf*>(&sm_pair[(32 + l31) * PAIR_LD + kt * 16 + l5 * 8]);
      acc0 = __builtin_amdgcn_mfma_f32_32x32x16_bf16(a0, B1[kt], acc0, 0, 0, 0);
      acc1 = __builtin_amdgcn_mfma_f32_32x32x16_bf16(a1, B1[kt], acc1, 0, 0, 0);
    }
#pragma unroll
    for (int r = 0; r < 16; ++r) {
      int m = (r & 3) + 8 * (r >> 2) + 4 * l5;
      sm_h1[m * H_LD + nb] = f2bf(fmaxf(acc0[r] + b1v, 0.f));
      sm_h1[(32 + m) * H_LD + nb] = f2bf(fmaxf(acc1[r] + b1v, 0.f));
    }
    __syncthreads();

    v16f c0, c1;
#pragma unroll
    for (int r = 0; r < 16; ++r) { c0[r] = 0.f; c1[r] = 0.f; }
#pragma unroll
    for (int kt = 0; kt < 8; ++kt) {
      v8bf a0 = *reinterpret_cast<const v8bf*>(&sm_h1[l31 * H_LD + kt * 16 + l5 * 8]);
      v8bf a1 = *reinterpret_cast<const v8bf*>(&sm_h1[(32 + l31) * H_LD + kt * 16 + l5 * 8]);
      c0 = __builtin_amdgcn_mfma_f32_32x32x16_bf16(a0, B2[kt], c0, 0, 0, 0);
      c1 = __builtin_amdgcn_mfma_f32_32x32x16_bf16(a1, B2[kt], c1, 0, 0, 0);
    }
#pragma unroll
    for (int r = 0; r < 16; ++r) {
      int m = (r & 3) + 8 * (r >> 2) + 4 * l5;
      sm_h2[m * H_LD + nb] = f2bf(fmaxf(c0[r] + b2v, 0.f));
      sm_h2[(32 + m) * H_LD + nb] = f2bf(fmaxf(c1[r] + b2v, 0.f));
    }
    __syncthreads();

    {
      int el = tid >> 2;
      const unsigned short* hrow = &sm_h2[el * H_LD + part * 32];
      const float* wrow = &sm_w3[part * 36];
      float sum = 0.f;
#pragma unroll
      for (int j = 0; j < 4; ++j) {
        uint4 u = *reinterpret_cast<const uint4*>(hrow + j * 8);
        float4 wa = *reinterpret_cast<const float4*>(wrow + j * 8);
        float4 wb = *reinterpret_cast<const float4*>(wrow + j * 8 + 4);
        sum += bfhi2f(u.x << 16) * wa.x + bfhi2f(u.x & 0xFFFF0000u) * wa.y;
        sum += bfhi2f(u.y << 16) * wa.z + bfhi2f(u.y & 0xFFFF0000u) * wa.w;
        sum += bfhi2f(u.z << 16) * wb.x + bfhi2f(u.z & 0xFFFF0000u) * wb.y;
        sum += bfhi2f(u.w << 16) * wb.z + bfhi2f(u.w & 0xFFFF0000u) * wb.w;
      }
      sum += __shfl_xor(sum, 1, 64);
      sum += __shfl_xor(sum, 2, 64);
      if (part == 0) out[e0 + el] = sum + bias3;
    }
  }
}

extern "C" void kernel_launch(void* const* d_in, const int* in_sizes, int n_in,
                              void* d_out, int out_size, void* d_ws, size_t ws_size,
                              hipStream_t stream) {
  const float* x1 = (const float*)d_in[0];
  const float* x2 = (const float*)d_in[1];
  const int* eidx = (const int*)d_in[2];
  const float* W1 = (const float*)d_in[3];
  const float* b1 = (const float*)d_in[4];
  const float* W2 = (const float*)d_in[5];
  const float* b2 = (const float*)d_in[6];
  const float* W3 = (const float*)d_in[7];
  const float* b3 = (const float*)d_in[8];
  float* out = (float*)d_out;

  int E = in_sizes[2] / 2;
  if (E <= 0) return;
  int ntiles = E / MTILE;           // E = 1,600,000 divisible by 64
  int nelem = in_sizes[0];          // nodes * DIM
  int nnodes = nelem / DIM;

  unsigned short* W1t = (unsigned short*)d_ws;         // 32768 bf16
  unsigned short* W2t = W1t + 32768;                   // 16384 bf16/fp16
  size_t woff = 98304;                                 // bytes used by weights
  size_t need = woff + 2 * (size_t)nelem * 2;          // y1c + y2c fp16
  int use_cache = (ws_size >= need) ? 1 : 0;
  unsigned short* y1c = (unsigned short*)((char*)d_ws + woff);
  unsigned short* y2c = y1c + nelem;

  prep_w<<<192, 256, 0, stream>>>(W1, W2, W1t, W2t, use_cache);

  if (use_cache) {
    int ntn = (nnodes + MTILE - 1) / MTILE;
    node_precompute<<<2 * ntn, 256, 0, stream>>>(x1, x2, W1t, b1, y1c, y2c, nnodes);
    // grid 1024 = 4 blocks/CU, matching the ~100-VGPR residency limit
    mlp_edge_y<<<1024, 256, 0, stream>>>(eidx, W2t, b2, W3, b3,
                                         out, E, ntiles, y1c, y2c);
  } else {
    mlp_edge_direct<<<512, 256, 0, stream>>>(x1, x2, eidx, W1t, W2t,
                                             b1, b2, W3, b3, out, E, ntiles);
  }
}

// Round 5
// 304.965 us; speedup vs baseline: 1.0105x; 1.0105x over previous
//
#include <hip/hip_runtime.h>
#include <cstdint>

#define DIM 128
#define MTILE 64        // nodes per precompute tile / fallback edge tile
#define ETILE 128       // edges per block-tile (edge kernel) -- round-5: 2x
#define PAIR_LD 264     // ushorts per pair row (256 + 8 pad) -- fallback kernel
#define H_LD 136        // ushorts per h row  (128 + 8 pad)

typedef __bf16 v8bf __attribute__((ext_vector_type(8)));
typedef _Float16 v8hf __attribute__((ext_vector_type(8)));
typedef float v16f __attribute__((ext_vector_type(16)));

static __device__ __forceinline__ unsigned int f2bf_pack(float a, float b) {
  union { float f; unsigned u; } x, y; x.f = a; y.f = b;
  unsigned lo = (x.u + 0x7FFFu + ((x.u >> 16) & 1u)) >> 16;
  unsigned hi = (y.u + 0x7FFFu + ((y.u >> 16) & 1u)) >> 16;
  return lo | (hi << 16);
}
static __device__ __forceinline__ unsigned short f2bf(float a) {
  union { float f; unsigned u; } x; x.f = a;
  return (unsigned short)((x.u + 0x7FFFu + ((x.u >> 16) & 1u)) >> 16);
}
static __device__ __forceinline__ unsigned short f2h(float a) {
  union { _Float16 h; unsigned short u; } c; c.h = (_Float16)a; return c.u;
}
static __device__ __forceinline__ float bfhi2f(unsigned int hi16) {
  union { unsigned u; float f; } c; c.u = hi16; return c.f;
}

// prep: weight transpose/convert only. W1t bf16 (node_precompute / fallback
// GEMM1); W2t fp16 when y-cached path runs, bf16 for the fallback.
__global__ __launch_bounds__(256) void prep_w(
    const float* __restrict__ W1, const float* __restrict__ W2,
    unsigned short* __restrict__ W1t, unsigned short* __restrict__ W2t,
    int w2_f16) {
  int i = blockIdx.x * 256 + threadIdx.x;
  if (i < 32768) {
    int n = i >> 8, k = i & 255;
    W1t[i] = f2bf(W1[k * 128 + n]);
  } else if (i < 49152) {
    int j = i - 32768;
    int n = j >> 7, k = j & 127;
    float v = W2[k * 128 + n];
    W2t[j] = w2_f16 ? f2h(v) : f2bf(v);
  }
}

// node_precompute v3: single LDS buffer (sm_y aliased onto sm_x, +1 barrier)
// -> 17.4 KB LDS, residency rises from 4 to ~5-6 blocks/CU (reg-limited),
// better hiding of the streamed x read. Both h-halves' accs held in regs
// (32) so all sm reads complete before the aliased overwrite.
__global__ __launch_bounds__(256, 4) void node_precompute(
    const float* __restrict__ x1, const float* __restrict__ x2,
    const unsigned short* __restrict__ W1t, const float* __restrict__ b1,
    unsigned short* __restrict__ y1c, unsigned short* __restrict__ y2c,
    int nnodes)
{
  __shared__ unsigned short sm[MTILE * H_LD];   // 17408 B: x tile, then y tile

  const int tid = threadIdx.x;
  const int lane = tid & 63;
  const int wv = tid >> 6;
  const int l31 = lane & 31;
  const int l5 = lane >> 5;
  const int nb = wv * 32 + l31;
  const int rslot = tid >> 4;
  const int lane16 = tid & 15;

  const int which = blockIdx.x & 1;          // 0: y1 = x1@W1_top, 1: y2 = x2@W1_bot + b1
  const int base = (blockIdx.x >> 1) * MTILE;
  const int nvalid = nnodes - base;          // < 64 only in the last tile
  const float* xs = which ? x2 : x1;
  unsigned short* yd = which ? y2c : y1c;

  v8bf B1[8];
#pragma unroll
  for (int kt = 0; kt < 8; ++kt)
    B1[kt] = *reinterpret_cast<const v8bf*>(W1t + nb * 256 + which * 128 + kt * 16 + l5 * 8);
  const float badd = which ? b1[nb] : 0.f;

  // stage x tile (fp32 -> bf16), coalesced 32B/thread
#pragma unroll
  for (int p = 0; p < 4; ++p) {
    int el = p * 16 + rslot;
    int row = base + el; if (row >= nnodes) row = nnodes - 1;
    const float4* s = reinterpret_cast<const float4*>(xs + (size_t)row * DIM) + lane16 * 2;
    float4 f0 = s[0];
    float4 f1 = s[1];
    uint4 pk;
    pk.x = f2bf_pack(f0.x, f0.y);
    pk.y = f2bf_pack(f0.z, f0.w);
    pk.z = f2bf_pack(f1.x, f1.y);
    pk.w = f2bf_pack(f1.z, f1.w);
    *reinterpret_cast<uint4*>(&sm[el * H_LD + lane16 * 8]) = pk;
  }
  __syncthreads();

  // both 32-row halves, accs kept live so all sm reads finish before alias
  v16f acc0, acc1;
#pragma unroll
  for (int r = 0; r < 16; ++r) { acc0[r] = 0.f; acc1[r] = 0.f; }
#pragma unroll
  for (int kt = 0; kt < 8; ++kt) {
    v8bf a0 = *reinterpret_cast<const v8bf*>(&sm[l31 * H_LD + kt * 16 + l5 * 8]);
    v8bf a1 = *reinterpret_cast<const v8bf*>(&sm[(32 + l31) * H_LD + kt * 16 + l5 * 8]);
    acc0 = __builtin_amdgcn_mfma_f32_32x32x16_bf16(a0, B1[kt], acc0, 0, 0, 0);
    acc1 = __builtin_amdgcn_mfma_f32_32x32x16_bf16(a1, B1[kt], acc1, 0, 0, 0);
  }
  __syncthreads();  // all x reads done -> safe to overwrite with y

#pragma unroll
  for (int r = 0; r < 16; ++r) {
    int m = (r & 3) + 8 * (r >> 2) + 4 * l5;  // C/D row map (m74/m101)
    sm[m * H_LD + nb] = f2h(acc0[r] + badd);
    sm[(32 + m) * H_LD + nb] = f2h(acc1[r] + badd);
  }
  __syncthreads();

  // coalesced fp16 write-out
#pragma unroll
  for (int p = 0; p < 4; ++p) {
    int el = p * 16 + rslot;
    if (el < nvalid)
      *reinterpret_cast<uint4*>(yd + (size_t)(base + el) * DIM + lane16 * 8) =
          *reinterpret_cast<const uint4*>(&sm[el * H_LD + lane16 * 8]);
  }
}

// Round-5 edge kernel: ETILE=128 (2x round-3). Round-4 proved register
// pipelining across barriers spills (VGPR pinned 64, WRITE 6.25->20.6MB);
// round-3 proved more blocks is a null. Remaining concurrency lever:
// MORE GATHER LOADS PER WAVE PER PHASE. 16 in-flight 16B gathers/thread
// (~32 lines/wave vs 16) between barriers, barrier count per edge halved.
// Transient peak ~64 regs with SHORT live range (issue->store same phase,
// r4-proven pattern); b2/W3 in LDS (sm_bw). Cap 128 regs at (256,4);
// LDS 37.9 KB -> 4 blocks/CU. Tripwire: WRITE_SIZE must stay ~6250 KB.
__global__ __launch_bounds__(256, 4) void mlp_edge_y(
    const int* __restrict__ eidx,
    const unsigned short* __restrict__ W2t,   // fp16 [n=128][k=128]
    const float* __restrict__ b2, const float* __restrict__ W3,
    const float* __restrict__ b3, float* __restrict__ out,
    int E, int ntiles,
    const unsigned short* __restrict__ y1c, const unsigned short* __restrict__ y2c)
{
  __shared__ unsigned short sm_h1[ETILE * H_LD];   // 34816 B
  __shared__ float sm_part[4 * ETILE];             // 2048 B: [wave][edge]
  __shared__ float2 sm_bw[DIM];                    // 1024 B: {b2[n], W3[n]}

  const int tid = threadIdx.x;
  const int lane = tid & 63;
  const int wv = tid >> 6;        // wave -> n-slice [32*wv, 32*wv+32)
  const int l31 = lane & 31;
  const int l5 = lane >> 5;
  const int nb = wv * 32 + l31;

  if (tid < 128) sm_bw[tid] = make_float2(b2[tid], W3[tid]);

  v8hf B2[8];
#pragma unroll
  for (int kt = 0; kt < 8; ++kt)
    B2[kt] = *reinterpret_cast<const v8hf*>(W2t + nb * 128 + kt * 16 + l5 * 8);
  const float bias3 = b3[0];
  const int n2b = wv * 32 + 4 * l5;   // n2(r) = n2b + (r&3) + 8*(r>>2)

  const int rslot = tid >> 4;     // 0..15: row slot within a gather pass
  const int lane16 = tid & 15;    // 16 lanes x 8 fp16 cover one 128-wide row

  // preamble: indices for the first tile (idxr[0..7]=src, [8..15]=dst)
  int idxr[16];
  {
    const int t0 = min((int)blockIdx.x, ntiles - 1);
    const size_t e0 = (size_t)t0 * ETILE;
#pragma unroll
    for (int p = 0; p < 16; ++p) {
      int el = (p & 7) * 16 + rslot;
      size_t ge = e0 + el; if (ge >= (size_t)E) ge = E - 1;   // last-tile clamp
      idxr[p] = eidx[ge + ((p >= 8) ? (size_t)E : 0)];
    }
  }

  int eprev = -1;

  for (int tile = blockIdx.x; tile < ntiles; tile += gridDim.x) {
    __syncthreads();  // A: sm_h1 free (GEMM2 readers done), partials ready

    // gather both endpoints of each edge-row slice (issue all 16 loads)
    uint4 av[8], bv[8];
#pragma unroll
    for (int p = 0; p < 8; ++p) {
      av[p] = *reinterpret_cast<const uint4*>(y1c + (size_t)idxr[p] * DIM + lane16 * 8);
      bv[p] = *reinterpret_cast<const uint4*>(y2c + (size_t)idxr[p + 8] * DIM + lane16 * 8);
    }

    // deferred final reduce of PREVIOUS tile (overlaps gather latency)
    if (eprev >= 0 && tid < ETILE && eprev + tid < E) {
      float s = sm_part[tid] + sm_part[128 + tid] + sm_part[256 + tid] + sm_part[384 + tid];
      out[eprev + tid] = s + bias3;
    }

    // h1 = relu(y1 + y2) in packed fp16, straight to LDS (short live range)
#pragma unroll
    for (int p = 0; p < 8; ++p) {
      union { uint4 u; v8hf h; } a, b;
      a.u = av[p]; b.u = bv[p];
      v8hf s = a.h + b.h;
#pragma unroll
      for (int j = 0; j < 8; ++j) s[j] = s[j] > (_Float16)0 ? s[j] : (_Float16)0;
      union { v8hf h; uint4 u; } r; r.h = s;
      int el = p * 16 + rslot;
      *reinterpret_cast<uint4*>(&sm_h1[el * H_LD + lane16 * 8]) = r.u;
    }

    // prefetch next tile's indices (16 scalar ints, land during GEMM2)
    {
      const int tn = min(tile + (int)gridDim.x, ntiles - 1);
      const size_t en = (size_t)tn * ETILE;
#pragma unroll
      for (int p = 0; p < 16; ++p) {
        int el = (p & 7) * 16 + rslot;
        size_t ge = en + el; if (ge >= (size_t)E) ge = E - 1;
        idxr[p] = eidx[ge + ((p >= 8) ? (size_t)E : 0)];
      }
    }
    __syncthreads();  // B: h1 ready

    // GEMM2 (transposed: h2^T = W2t @ h1^T) + GEMM3 via LDS-resident b2/W3
#pragma unroll
    for (int h = 0; h < 4; ++h) {
      v16f acc;
#pragma unroll
      for (int r = 0; r < 16; ++r) acc[r] = 0.f;
#pragma unroll
      for (int kt = 0; kt < 8; ++kt) {
        v8hf bf = *reinterpret_cast<const v8hf*>(&sm_h1[(32 * h + l31) * H_LD + kt * 16 + l5 * 8]);
        acc = __builtin_amdgcn_mfma_f32_32x32x16_f16(B2[kt], bf, acc, 0, 0, 0);
      }
      float p = 0.f;
#pragma unroll
      for (int r = 0; r < 16; ++r) {
        float2 bw = sm_bw[n2b + (r & 3) + 8 * (r >> 2)];  // broadcast read
        p += fmaxf(acc[r] + bw.x, 0.f) * bw.y;
      }
      p += __shfl_xor(p, 32);          // combine l5 halves
      if (l5 == 0) sm_part[wv * 128 + 32 * h + l31] = p;
    }

    eprev = tile * ETILE;
  }

  // ---- epilogue: reduce the last tile's partials ----
  __syncthreads();
  if (eprev >= 0 && tid < ETILE && eprev + tid < E) {
    float s = sm_part[tid] + sm_part[128 + tid] + sm_part[256 + tid] + sm_part[384 + tid];
    out[eprev + tid] = s + bias3;
  }
}

// Fallback (ws too small for y cache): unchanged round-6 structure.
__global__ __launch_bounds__(256, 2) void mlp_edge_direct(
    const float* __restrict__ x1, const float* __restrict__ x2,
    const int* __restrict__ eidx,
    const unsigned short* __restrict__ W1t, const unsigned short* __restrict__ W2t,
    const float* __restrict__ b1, const float* __restrict__ b2,
    const float* __restrict__ W3, const float* __restrict__ b3,
    float* __restrict__ out, int E, int ntiles)
{
  __shared__ unsigned short sm_pair[MTILE * PAIR_LD];
  __shared__ unsigned short sm_h1[MTILE * H_LD];
  __shared__ float sm_w3[4 * 36];
  unsigned short* sm_h2 = sm_pair;

  const int tid = threadIdx.x;
  const int lane = tid & 63;
  const int wv = tid >> 6;
  const int l31 = lane & 31;
  const int l5 = lane >> 5;
  const int nb = wv * 32 + l31;

  v8bf B1[16], B2[8];
#pragma unroll
  for (int kt = 0; kt < 16; ++kt)
    B1[kt] = *reinterpret_cast<const v8bf*>(W1t + nb * 256 + kt * 16 + l5 * 8);
#pragma unroll
  for (int kt = 0; kt < 8; ++kt)
    B2[kt] = *reinterpret_cast<const v8bf*>(W2t + nb * 128 + kt * 16 + l5 * 8);
  const float b1v = b1[nb];
  const float b2v = b2[nb];
  const float bias3 = b3[0];
  if (tid < 128) sm_w3[(tid >> 5) * 36 + (tid & 31)] = W3[tid];

  const int rslot = tid >> 4;
  const int lane16 = tid & 15;
  const int part = tid & 3;

  for (int tile = blockIdx.x; tile < ntiles; tile += gridDim.x) {
    __syncthreads();
    const int e0 = tile * MTILE;
#pragma unroll
    for (int p = 0; p < 8; ++p) {
      int rowid = p * 16 + rslot;
      int half = rowid >> 6;
      int el = rowid & 63;
      int node = eidx[e0 + el + (half ? E : 0)];
      const float* src = (half ? x2 : x1) + (size_t)node * DIM + lane16 * 8;
      float4 f0 = *reinterpret_cast<const float4*>(src);
      float4 f1 = *reinterpret_cast<const float4*>(src + 4);
      uint4 pk;
      pk.x = f2bf_pack(f0.x, f0.y);
      pk.y = f2bf_pack(f0.z, f0.w);
      pk.z = f2bf_pack(f1.x, f1.y);
      pk.w = f2bf_pack(f1.z, f1.w);
      *reinterpret_cast<uint4*>(&sm_pair[el * PAIR_LD + half * 128 + lane16 * 8]) = pk;
    }
    __syncthreads();

    v16f acc0, acc1;
#pragma unroll
    for (int r = 0; r < 16; ++r) { acc0[r] = 0.f; acc1[r] = 0.f; }
#pragma unroll
    for (int kt = 0; kt < 16; ++kt) {
      v8bf a0 = *reinterpret_cast<const v8bf*>(&sm_pair[l31 * PAIR_LD + kt * 16 + l5 * 8]);
      v8bf a1 = *reinterpret_cast<const v8bf*>(&sm_pair[(32 + l31) * PAIR_LD + kt * 16 + l5 * 8]);
      acc0 = __builtin_amdgcn_mfma_f32_32x32x16_bf16(a0, B1[kt], acc0, 0, 0, 0);
      acc1 = __builtin_amdgcn_mfma_f32_32x32x16_bf16(a1, B1[kt], acc1, 0, 0, 0);
    }
#pragma unroll
    for (int r = 0; r < 16; ++r) {
      int m = (r & 3) + 8 * (r >> 2) + 4 * l5;
      sm_h1[m * H_LD + nb] = f2bf(fmaxf(acc0[r] + b1v, 0.f));
      sm_h1[(32 + m) * H_LD + nb] = f2bf(fmaxf(acc1[r] + b1v, 0.f));
    }
    __syncthreads();

    v16f c0, c1;
#pragma unroll
    for (int r = 0; r < 16; ++r) { c0[r] = 0.f; c1[r] = 0.f; }
#pragma unroll
    for (int kt = 0; kt < 8; ++kt) {
      v8bf a0 = *reinterpret_cast<const v8bf*>(&sm_h1[l31 * H_LD + kt * 16 + l5 * 8]);
      v8bf a1 = *reinterpret_cast<const v8bf*>(&sm_h1[(32 + l31) * H_LD + kt * 16 + l5 * 8]);
      c0 = __builtin_amdgcn_mfma_f32_32x32x16_bf16(a0, B2[kt], c0, 0, 0, 0);
      c1 = __builtin_amdgcn_mfma_f32_32x32x16_bf16(a1, B2[kt], c1, 0, 0, 0);
    }
#pragma unroll
    for (int r = 0; r < 16; ++r) {
      int m = (r & 3) + 8 * (r >> 2) + 4 * l5;
      sm_h2[m * H_LD + nb] = f2bf(fmaxf(c0[r] + b2v, 0.f));
      sm_h2[(32 + m) * H_LD + nb] = f2bf(fmaxf(c1[r] + b2v, 0.f));
    }
    __syncthreads();

    {
      int el = tid >> 2;
      const unsigned short* hrow = &sm_h2[el * H_LD + part * 32];
      const float* wrow = &sm_w3[part * 36];
      float sum = 0.f;
#pragma unroll
      for (int j = 0; j < 4; ++j) {
        uint4 u = *reinterpret_cast<const uint4*>(hrow + j * 8);
        float4 wa = *reinterpret_cast<const float4*>(wrow + j * 8);
        float4 wb = *reinterpret_cast<const float4*>(wrow + j * 8 + 4);
        sum += bfhi2f(u.x << 16) * wa.x + bfhi2f(u.x & 0xFFFF0000u) * wa.y;
        sum += bfhi2f(u.y << 16) * wa.z + bfhi2f(u.y & 0xFFFF0000u) * wa.w;
        sum += bfhi2f(u.z << 16) * wb.x + bfhi2f(u.z & 0xFFFF0000u) * wb.y;
        sum += bfhi2f(u.w << 16) * wb.z + bfhi2f(u.w & 0xFFFF0000u) * wb.w;
      }
      sum += __shfl_xor(sum, 1, 64);
      sum += __shfl_xor(sum, 2, 64);
      if (part == 0) out[e0 + el] = sum + bias3;
    }
  }
}

extern "C" void kernel_launch(void* const* d_in, const int* in_sizes, int n_in,
                              void* d_out, int out_size, void* d_ws, size_t ws_size,
                              hipStream_t stream) {
  const float* x1 = (const float*)d_in[0];
  const float* x2 = (const float*)d_in[1];
  const int* eidx = (const int*)d_in[2];
  const float* W1 = (const float*)d_in[3];
  const float* b1 = (const float*)d_in[4];
  const float* W2 = (const float*)d_in[5];
  const float* b2 = (const float*)d_in[6];
  const float* W3 = (const float*)d_in[7];
  const float* b3 = (const float*)d_in[8];
  float* out = (float*)d_out;

  int E = in_sizes[2] / 2;
  if (E <= 0) return;
  int nelem = in_sizes[0];          // nodes * DIM
  int nnodes = nelem / DIM;

  unsigned short* W1t = (unsigned short*)d_ws;         // 32768 bf16
  unsigned short* W2t = W1t + 32768;                   // 16384 bf16/fp16
  size_t woff = 98304;                                 // bytes used by weights
  size_t need = woff + 2 * (size_t)nelem * 2;          // y1c + y2c fp16
  int use_cache = (ws_size >= need) ? 1 : 0;
  unsigned short* y1c = (unsigned short*)((char*)d_ws + woff);
  unsigned short* y2c = y1c + nelem;

  prep_w<<<192, 256, 0, stream>>>(W1, W2, W1t, W2t, use_cache);

  if (use_cache) {
    int ntn = (nnodes + MTILE - 1) / MTILE;
    node_precompute<<<2 * ntn, 256, 0, stream>>>(x1, x2, W1t, b1, y1c, y2c, nnodes);
    int ntiles = (E + ETILE - 1) / ETILE;
    int grid = ntiles < 1024 ? ntiles : 1024;   // 4 blocks/CU (LDS-limited)
    mlp_edge_y<<<grid, 256, 0, stream>>>(eidx, W2t, b2, W3, b3,
                                         out, E, ntiles, y1c, y2c);
  } else {
    int ntiles = E / MTILE;
    mlp_edge_direct<<<512, 256, 0, stream>>>(x1, x2, eidx, W1t, W2t,
                                             b1, b2, W3, b3, out, E, ntiles);
  }
}

// Round 6
// 260.666 us; speedup vs baseline: 1.1823x; 1.1699x over previous
//
#include <hip/hip_runtime.h>
#include <cstdint>

#define DIM 128
#define MTILE 64        // nodes per precompute tile / fallback edge tile
#define ETILE 64        // edges per block-tile (edge kernel)
#define PAIR_LD 264     // ushorts per pair row (256 + 8 pad) -- fallback kernel
#define H_LD 136        // ushorts per h row  (128 + 8 pad) -- precompute/fallback

typedef __bf16 v8bf __attribute__((ext_vector_type(8)));
typedef _Float16 v8hf __attribute__((ext_vector_type(8)));
typedef float v16f __attribute__((ext_vector_type(16)));

static __device__ __forceinline__ unsigned int f2bf_pack(float a, float b) {
  union { float f; unsigned u; } x, y; x.f = a; y.f = b;
  unsigned lo = (x.u + 0x7FFFu + ((x.u >> 16) & 1u)) >> 16;
  unsigned hi = (y.u + 0x7FFFu + ((y.u >> 16) & 1u)) >> 16;
  return lo | (hi << 16);
}
static __device__ __forceinline__ unsigned short f2bf(float a) {
  union { float f; unsigned u; } x; x.f = a;
  return (unsigned short)((x.u + 0x7FFFu + ((x.u >> 16) & 1u)) >> 16);
}
static __device__ __forceinline__ unsigned short f2h(float a) {
  union { _Float16 h; unsigned short u; } c; c.h = (_Float16)a; return c.u;
}
static __device__ __forceinline__ float bfhi2f(unsigned int hi16) {
  union { unsigned u; float f; } c; c.u = hi16; return c.f;
}

// Direct HBM->LDS, 16B/lane. Global address is PER-LANE (gather ok);
// LDS dest is wave-uniform base + lane*16 (must be linear/unpadded).
static __device__ __forceinline__ void gload16(const void* g, void* l) {
  __builtin_amdgcn_global_load_lds(
      (const __attribute__((address_space(1))) unsigned int*)g,
      (__attribute__((address_space(3))) unsigned int*)l, 16, 0, 0);
}

// prep: weight transpose/convert only. W1t bf16 (node_precompute / fallback
// GEMM1); W2t fp16 when y-cached path runs, bf16 for the fallback.
__global__ __launch_bounds__(256) void prep_w(
    const float* __restrict__ W1, const float* __restrict__ W2,
    unsigned short* __restrict__ W1t, unsigned short* __restrict__ W2t,
    int w2_f16) {
  int i = blockIdx.x * 256 + threadIdx.x;
  if (i < 32768) {
    int n = i >> 8, k = i & 255;
    W1t[i] = f2bf(W1[k * 128 + n]);
  } else if (i < 49152) {
    int j = i - 32768;
    int n = j >> 7, k = j & 127;
    float v = W2[k * 128 + n];
    W2t[j] = w2_f16 ? f2h(v) : f2bf(v);
  }
}

// node_precompute v3 (round-5, kept -- passed): single aliased LDS buffer.
__global__ __launch_bounds__(256, 4) void node_precompute(
    const float* __restrict__ x1, const float* __restrict__ x2,
    const unsigned short* __restrict__ W1t, const float* __restrict__ b1,
    unsigned short* __restrict__ y1c, unsigned short* __restrict__ y2c,
    int nnodes)
{
  __shared__ unsigned short sm[MTILE * H_LD];   // x tile, then y tile

  const int tid = threadIdx.x;
  const int lane = tid & 63;
  const int wv = tid >> 6;
  const int l31 = lane & 31;
  const int l5 = lane >> 5;
  const int nb = wv * 32 + l31;
  const int rslot = tid >> 4;
  const int lane16 = tid & 15;

  const int which = blockIdx.x & 1;          // 0: y1 = x1@W1_top, 1: y2 = x2@W1_bot + b1
  const int base = (blockIdx.x >> 1) * MTILE;
  const int nvalid = nnodes - base;          // < 64 only in the last tile
  const float* xs = which ? x2 : x1;
  unsigned short* yd = which ? y2c : y1c;

  v8bf B1[8];
#pragma unroll
  for (int kt = 0; kt < 8; ++kt)
    B1[kt] = *reinterpret_cast<const v8bf*>(W1t + nb * 256 + which * 128 + kt * 16 + l5 * 8);
  const float badd = which ? b1[nb] : 0.f;

#pragma unroll
  for (int p = 0; p < 4; ++p) {
    int el = p * 16 + rslot;
    int row = base + el; if (row >= nnodes) row = nnodes - 1;
    const float4* s = reinterpret_cast<const float4*>(xs + (size_t)row * DIM) + lane16 * 2;
    float4 f0 = s[0];
    float4 f1 = s[1];
    uint4 pk;
    pk.x = f2bf_pack(f0.x, f0.y);
    pk.y = f2bf_pack(f0.z, f0.w);
    pk.z = f2bf_pack(f1.x, f1.y);
    pk.w = f2bf_pack(f1.z, f1.w);
    *reinterpret_cast<uint4*>(&sm[el * H_LD + lane16 * 8]) = pk;
  }
  __syncthreads();

  v16f acc0, acc1;
#pragma unroll
  for (int r = 0; r < 16; ++r) { acc0[r] = 0.f; acc1[r] = 0.f; }
#pragma unroll
  for (int kt = 0; kt < 8; ++kt) {
    v8bf a0 = *reinterpret_cast<const v8bf*>(&sm[l31 * H_LD + kt * 16 + l5 * 8]);
    v8bf a1 = *reinterpret_cast<const v8bf*>(&sm[(32 + l31) * H_LD + kt * 16 + l5 * 8]);
    acc0 = __builtin_amdgcn_mfma_f32_32x32x16_bf16(a0, B1[kt], acc0, 0, 0, 0);
    acc1 = __builtin_amdgcn_mfma_f32_32x32x16_bf16(a1, B1[kt], acc1, 0, 0, 0);
  }
  __syncthreads();  // all x reads done -> safe to overwrite with y

#pragma unroll
  for (int r = 0; r < 16; ++r) {
    int m = (r & 3) + 8 * (r >> 2) + 4 * l5;  // C/D row map (m74/m101)
    sm[m * H_LD + nb] = f2h(acc0[r] + badd);
    sm[(32 + m) * H_LD + nb] = f2h(acc1[r] + badd);
  }
  __syncthreads();

#pragma unroll
  for (int p = 0; p < 4; ++p) {
    int el = p * 16 + rslot;
    if (el < nvalid)
      *reinterpret_cast<uint4*>(yd + (size_t)(base + el) * DIM + lane16 * 8) =
          *reinterpret_cast<const uint4*>(&sm[el * H_LD + lane16 * 8]);
  }
}

// Round-6 edge kernel: zero-register pipelined gather via global_load_lds.
// r4/r5 proved the allocator spills ANY >=32-reg payload held across the
// MFMA region (VGPR pinned 64, WRITE 20-53MB). global_load_lds needs no
// VGPRs: tile t+1's 8 wave-calls (4 rows x 256B each, unpadded staging)
// are issued mid-iteration and stay in flight across GEMM2 + a RAW
// s_barrier (no vmcnt drain -- __syncthreads would re-drain, m97 lesson),
// waited only at the next iteration's explicit vmcnt(0).
// h1 = relu(y1+y2) is written IN-PLACE into the y1 staging region with a
// 4-bit XOR swizzle (col ^= (row&15)<<3 ushorts): staging dest stays
// linear (gload requirement), GEMM2 reads spread 32 lanes over 16 slots
// (2/bank = free, m136). LDS 66.5KB -> 2 blocks/CU; pipelining replaces
// occupancy. Tripwire: WRITE_SIZE must stay ~6250 KB, FETCH ~390 MB.
__global__ __launch_bounds__(256, 2) void mlp_edge_y(
    const int* __restrict__ eidx,
    const unsigned short* __restrict__ W2t,   // fp16 [n=128][k=128]
    const float* __restrict__ b2, const float* __restrict__ W3,
    const float* __restrict__ b3, float* __restrict__ out,
    int E, int ntiles,
    const unsigned short* __restrict__ y1c, const unsigned short* __restrict__ y2c)
{
  __shared__ unsigned short sm_y1[2][ETILE][DIM];  // 32768 B (h1 lives here too)
  __shared__ unsigned short sm_y2[2][ETILE][DIM];  // 32768 B
  __shared__ float sm_part[4 * ETILE];             // 1024 B: [wave][edge]

  const int tid = threadIdx.x;
  const int lane = tid & 63;
  const int wv = tid >> 6;        // wave -> n-slice [32*wv, 32*wv+32)
  const int l31 = lane & 31;
  const int l5 = lane >> 5;
  const int nb = wv * 32 + l31;

  if (blockIdx.x >= ntiles) return;

  v8hf B2[8];
#pragma unroll
  for (int kt = 0; kt < 8; ++kt)
    B2[kt] = *reinterpret_cast<const v8hf*>(W2t + nb * 128 + kt * 16 + l5 * 8);
  const float bias3 = b3[0];

  float w3r[16], b2r[16];
#pragma unroll
  for (int r = 0; r < 16; ++r) {
    int n2 = wv * 32 + (r & 3) + 8 * (r >> 2) + 4 * l5;
    w3r[r] = W3[n2];
    b2r[r] = b2[n2];
  }

  const int rslot = tid >> 4;     // 0..15: edge-row slot; rows of a wave are contiguous
  const int lane16 = tid & 15;    // 16 lanes x 8 fp16 cover one 128-wide row
  const int G = gridDim.x;

  // ---- preamble: idx(t0), issue staging(t0)->buf0, idx(t0+G) ----
  int idxr[8];
  {
    const size_t e0 = (size_t)blockIdx.x * ETILE;
#pragma unroll
    for (int p = 0; p < 8; ++p) {
      int el = (p & 3) * 16 + rslot;
      idxr[p] = eidx[e0 + el + ((p >= 4) ? (size_t)E : 0)];
    }
#pragma unroll
    for (int p = 0; p < 4; ++p) {
      gload16(y1c + (size_t)idxr[p] * DIM + lane16 * 8, &sm_y1[0][p * 16 + wv * 4][0]);
      gload16(y2c + (size_t)idxr[p + 4] * DIM + lane16 * 8, &sm_y2[0][p * 16 + wv * 4][0]);
    }
    const int t1 = min((int)blockIdx.x + G, ntiles - 1);
    const size_t e1 = (size_t)t1 * ETILE;
#pragma unroll
    for (int p = 0; p < 8; ++p) {
      int el = (p & 3) * 16 + rslot;
      idxr[p] = eidx[e1 + el + ((p >= 4) ? (size_t)E : 0)];
    }
  }

  int eprev = -1;
  int cur = 0;

  for (int tile = blockIdx.x; tile < ntiles; tile += G) {
    // wait tile t's staging (own wave's loads; issued a full iteration ago),
    // and drain own LDS ops; then RAW barrier (no compiler vmcnt re-drain).
    asm volatile("s_waitcnt vmcnt(0) lgkmcnt(0)" ::: "memory");
    __builtin_amdgcn_s_barrier();                  // A
    __builtin_amdgcn_sched_barrier(0);

    // deferred final reduce of PREVIOUS tile (sm_part sealed by barrier A)
    if (eprev >= 0 && tid < ETILE) {
      float s = sm_part[tid] + sm_part[64 + tid] + sm_part[128 + tid] + sm_part[192 + tid];
      out[eprev + tid] = s + bias3;
    }

    // retire tile t: h1 = relu(y1+y2), swizzled in-place into y1 region.
    // Each row is owned by 16 contiguous tids (one wave): reads of a row
    // complete before its swizzled overwrite (lockstep, in-order LDS).
#pragma unroll
    for (int p = 0; p < 4; ++p) {
      int el = p * 16 + rslot;
      uint4 ua = *reinterpret_cast<const uint4*>(&sm_y1[cur][el][lane16 * 8]);
      uint4 ub = *reinterpret_cast<const uint4*>(&sm_y2[cur][el][lane16 * 8]);
      union { uint4 u; v8hf h; } a, b; a.u = ua; b.u = ub;
      v8hf s = a.h + b.h;
#pragma unroll
      for (int j = 0; j < 8; ++j) s[j] = s[j] > (_Float16)0 ? s[j] : (_Float16)0;
      union { v8hf h; uint4 u; } r; r.h = s;
      *reinterpret_cast<uint4*>(&sm_y1[cur][el][(lane16 * 8) ^ (rslot << 3)]) = r.u;
    }

    // issue tile t+G into buf cur^1 (zero VGPR payload; flies across GEMM2,
    // barrier B, and barrier A of the next iteration)
    if (tile + G < ntiles) {
#pragma unroll
      for (int p = 0; p < 4; ++p) {
        gload16(y1c + (size_t)idxr[p] * DIM + lane16 * 8, &sm_y1[cur ^ 1][p * 16 + wv * 4][0]);
        gload16(y2c + (size_t)idxr[p + 4] * DIM + lane16 * 8, &sm_y2[cur ^ 1][p * 16 + wv * 4][0]);
      }
      const int tn = min(tile + 2 * G, ntiles - 1);
      const size_t en = (size_t)tn * ETILE;
#pragma unroll
      for (int p = 0; p < 8; ++p) {
        int el = (p & 3) * 16 + rslot;
        idxr[p] = eidx[en + el + ((p >= 4) ? (size_t)E : 0)];
      }
    }

    // h1 writes visible; do NOT drain vmcnt here (the whole point)
    asm volatile("s_waitcnt lgkmcnt(0)" ::: "memory");
    __builtin_amdgcn_s_barrier();                  // B
    __builtin_amdgcn_sched_barrier(0);

    // GEMM2 (transposed: h2^T = W2t @ h1^T, swizzled reads) + GEMM3
#pragma unroll
    for (int h = 0; h < 2; ++h) {
      v16f acc;
#pragma unroll
      for (int r = 0; r < 16; ++r) acc[r] = b2r[r];  // bias-init
#pragma unroll
      for (int kt = 0; kt < 8; ++kt) {
        int row = 32 * h + l31;
        int col = (kt * 16 + l5 * 8) ^ ((l31 & 15) << 3);
        v8hf bf = *reinterpret_cast<const v8hf*>(&sm_y1[cur][row][col]);
        acc = __builtin_amdgcn_mfma_f32_32x32x16_f16(B2[kt], bf, acc, 0, 0, 0);
      }
      float p = 0.f;
#pragma unroll
      for (int r = 0; r < 16; ++r) p += fmaxf(acc[r], 0.f) * w3r[r];
      p += __shfl_xor(p, 32);          // combine l5 halves
      if (l5 == 0) sm_part[wv * 64 + 32 * h + l31] = p;
    }

    eprev = tile * ETILE;
    cur ^= 1;
  }

  // ---- epilogue: reduce the last tile's partials ----
  __syncthreads();
  if (eprev >= 0 && tid < ETILE) {
    float s = sm_part[tid] + sm_part[64 + tid] + sm_part[128 + tid] + sm_part[192 + tid];
    out[eprev + tid] = s + bias3;
  }
}

// Fallback (ws too small for y cache): unchanged round-6 structure.
__global__ __launch_bounds__(256, 2) void mlp_edge_direct(
    const float* __restrict__ x1, const float* __restrict__ x2,
    const int* __restrict__ eidx,
    const unsigned short* __restrict__ W1t, const unsigned short* __restrict__ W2t,
    const float* __restrict__ b1, const float* __restrict__ b2,
    const float* __restrict__ W3, const float* __restrict__ b3,
    float* __restrict__ out, int E, int ntiles)
{
  __shared__ unsigned short sm_pair[MTILE * PAIR_LD];
  __shared__ unsigned short sm_h1[MTILE * H_LD];
  __shared__ float sm_w3[4 * 36];
  unsigned short* sm_h2 = sm_pair;

  const int tid = threadIdx.x;
  const int lane = tid & 63;
  const int wv = tid >> 6;
  const int l31 = lane & 31;
  const int l5 = lane >> 5;
  const int nb = wv * 32 + l31;

  v8bf B1[16], B2[8];
#pragma unroll
  for (int kt = 0; kt < 16; ++kt)
    B1[kt] = *reinterpret_cast<const v8bf*>(W1t + nb * 256 + kt * 16 + l5 * 8);
#pragma unroll
  for (int kt = 0; kt < 8; ++kt)
    B2[kt] = *reinterpret_cast<const v8bf*>(W2t + nb * 128 + kt * 16 + l5 * 8);
  const float b1v = b1[nb];
  const float b2v = b2[nb];
  const float bias3 = b3[0];
  if (tid < 128) sm_w3[(tid >> 5) * 36 + (tid & 31)] = W3[tid];

  const int rslot = tid >> 4;
  const int lane16 = tid & 15;
  const int part = tid & 3;

  for (int tile = blockIdx.x; tile < ntiles; tile += gridDim.x) {
    __syncthreads();
    const int e0 = tile * MTILE;
#pragma unroll
    for (int p = 0; p < 8; ++p) {
      int rowid = p * 16 + rslot;
      int half = rowid >> 6;
      int el = rowid & 63;
      int node = eidx[e0 + el + (half ? E : 0)];
      const float* src = (half ? x2 : x1) + (size_t)node * DIM + lane16 * 8;
      float4 f0 = *reinterpret_cast<const float4*>(src);
      float4 f1 = *reinterpret_cast<const float4*>(src + 4);
      uint4 pk;
      pk.x = f2bf_pack(f0.x, f0.y);
      pk.y = f2bf_pack(f0.z, f0.w);
      pk.z = f2bf_pack(f1.x, f1.y);
      pk.w = f2bf_pack(f1.z, f1.w);
      *reinterpret_cast<uint4*>(&sm_pair[el * PAIR_LD + half * 128 + lane16 * 8]) = pk;
    }
    __syncthreads();

    v16f acc0, acc1;
#pragma unroll
    for (int r = 0; r < 16; ++r) { acc0[r] = 0.f; acc1[r] = 0.f; }
#pragma unroll
    for (int kt = 0; kt < 16; ++kt) {
      v8bf a0 = *reinterpret_cast<const v8bf*>(&sm_pair[l31 * PAIR_LD + kt * 16 + l5 * 8]);
      v8bf a1 = *reinterpret_cast<const v8bf*>(&sm_pair[(32 + l31) * PAIR_LD + kt * 16 + l5 * 8]);
      acc0 = __builtin_amdgcn_mfma_f32_32x32x16_bf16(a0, B1[kt], acc0, 0, 0, 0);
      acc1 = __builtin_amdgcn_mfma_f32_32x32x16_bf16(a1, B1[kt], acc1, 0, 0, 0);
    }
#pragma unroll
    for (int r = 0; r < 16; ++r) {
      int m = (r & 3) + 8 * (r >> 2) + 4 * l5;
      sm_h1[m * H_LD + nb] = f2bf(fmaxf(acc0[r] + b1v, 0.f));
      sm_h1[(32 + m) * H_LD + nb] = f2bf(fmaxf(acc1[r] + b1v, 0.f));
    }
    __syncthreads();

    v16f c0, c1;
#pragma unroll
    for (int r = 0; r < 16; ++r) { c0[r] = 0.f; c1[r] = 0.f; }
#pragma unroll
    for (int kt = 0; kt < 8; ++kt) {
      v8bf a0 = *reinterpret_cast<const v8bf*>(&sm_h1[l31 * H_LD + kt * 16 + l5 * 8]);
      v8bf a1 = *reinterpret_cast<const v8bf*>(&sm_h1[(32 + l31) * H_LD + kt * 16 + l5 * 8]);
      c0 = __builtin_amdgcn_mfma_f32_32x32x16_bf16(a0, B2[kt], c0, 0, 0, 0);
      c1 = __builtin_amdgcn_mfma_f32_32x32x16_bf16(a1, B2[kt], c1, 0, 0, 0);
    }
#pragma unroll
    for (int r = 0; r < 16; ++r) {
      int m = (r & 3) + 8 * (r >> 2) + 4 * l5;
      sm_h2[m * H_LD + nb] = f2bf(fmaxf(c0[r] + b2v, 0.f));
      sm_h2[(32 + m) * H_LD + nb] = f2bf(fmaxf(c1[r] + b2v, 0.f));
    }
    __syncthreads();

    {
      int el = tid >> 2;
      const unsigned short* hrow = &sm_h2[el * H_LD + part * 32];
      const float* wrow = &sm_w3[part * 36];
      float sum = 0.f;
#pragma unroll
      for (int j = 0; j < 4; ++j) {
        uint4 u = *reinterpret_cast<const uint4*>(hrow + j * 8);
        float4 wa = *reinterpret_cast<const float4*>(wrow + j * 8);
        float4 wb = *reinterpret_cast<const float4*>(wrow + j * 8 + 4);
        sum += bfhi2f(u.x << 16) * wa.x + bfhi2f(u.x & 0xFFFF0000u) * wa.y;
        sum += bfhi2f(u.y << 16) * wa.z + bfhi2f(u.y & 0xFFFF0000u) * wa.w;
        sum += bfhi2f(u.z << 16) * wb.x + bfhi2f(u.z & 0xFFFF0000u) * wb.y;
        sum += bfhi2f(u.w << 16) * wb.z + bfhi2f(u.w & 0xFFFF0000u) * wb.w;
      }
      sum += __shfl_xor(sum, 1, 64);
      sum += __shfl_xor(sum, 2, 64);
      if (part == 0) out[e0 + el] = sum + bias3;
    }
  }
}

extern "C" void kernel_launch(void* const* d_in, const int* in_sizes, int n_in,
                              void* d_out, int out_size, void* d_ws, size_t ws_size,
                              hipStream_t stream) {
  const float* x1 = (const float*)d_in[0];
  const float* x2 = (const float*)d_in[1];
  const int* eidx = (const int*)d_in[2];
  const float* W1 = (const float*)d_in[3];
  const float* b1 = (const float*)d_in[4];
  const float* W2 = (const float*)d_in[5];
  const float* b2 = (const float*)d_in[6];
  const float* W3 = (const float*)d_in[7];
  const float* b3 = (const float*)d_in[8];
  float* out = (float*)d_out;

  int E = in_sizes[2] / 2;
  if (E <= 0) return;
  int nelem = in_sizes[0];          // nodes * DIM
  int nnodes = nelem / DIM;

  unsigned short* W1t = (unsigned short*)d_ws;         // 32768 bf16
  unsigned short* W2t = W1t + 32768;                   // 16384 bf16/fp16
  size_t woff = 98304;                                 // bytes used by weights
  size_t need = woff + 2 * (size_t)nelem * 2;          // y1c + y2c fp16
  int use_cache = (ws_size >= need) ? 1 : 0;
  unsigned short* y1c = (unsigned short*)((char*)d_ws + woff);
  unsigned short* y2c = y1c + nelem;

  prep_w<<<192, 256, 0, stream>>>(W1, W2, W1t, W2t, use_cache);

  if (use_cache) {
    int ntn = (nnodes + MTILE - 1) / MTILE;
    node_precompute<<<2 * ntn, 256, 0, stream>>>(x1, x2, W1t, b1, y1c, y2c, nnodes);
    int ntiles = E / ETILE;                  // E divisible by 64
    int grid = ntiles < 512 ? ntiles : 512;  // 2 blocks/CU (LDS-limited)
    mlp_edge_y<<<grid, 256, 0, stream>>>(eidx, W2t, b2, W3, b3,
                                         out, E, ntiles, y1c, y2c);
  } else {
    int ntiles = E / MTILE;
    mlp_edge_direct<<<512, 256, 0, stream>>>(x1, x2, eidx, W1t, W2t,
                                             b1, b2, W3, b3, out, E, ntiles);
  }
}